// Round 7
// baseline (675.268 us; speedup 1.0000x reference)
//
#include <hip/hip_runtime.h>
#include <math.h>

// Problem constants (from reference)
constexpr int NQ    = 14;        // qubits
constexpr int DIM   = 16384;     // 2^14 state dim
constexpr int BATCH = 4;
constexpr int SEQ   = 2048;
constexpr int NPOS  = BATCH * SEQ;   // 8192 (b,s) positions
constexpr int TPB   = 256;

constexpr int PCOMP = 16;                  // positions per compute block
constexpr int NCOMP = NPOS / PCOMP;        // 512 compute blocks
constexpr int NFILL = 1024;                // fill blocks (grid-stride sweep)

typedef float vf4 __attribute__((ext_vector_type(4)));

// out[b,s,:] is zero except the first complex element:
//   out[b,s,0] = total * softmax(z)[0],  z = tanh(x*W1+b1) @ W2 + b2
//
// R6: mimic rocclr fillBufferAligned for the zero region. Evidence: the
// poison fill (plain stores, small grid, grid-stride linear sweep) sustains
// 6.28 TB/s every iteration; our R5 fill (nt stores, 4096 chunked blocks)
// and R4's graph-node memset both ran ~4 TB/s. This version:
//   - blocks [0, NCOMP): R4's proven compute body; writes ONLY the 16-byte
//     row heads {re, im, 0, 0}.
//   - blocks [NCOMP, NCOMP+NFILL): ONE linear grid-stride float4 sweep of the
//     whole output with PLAIN stores, skipping row heads via predicate
//     (i4 & (ROW_F/4 - 1)) != 0. Sliding ~4MB contiguous window chip-wide =
//     HBM-row-friendly, exactly like rocclr's fill.
// Disjoint byte ranges -> no ordering needed (R5 proved sub-line sharing
// across blocks is correct: passed with absmax 1.8e-12).

template <bool CPLX>
__global__ void __launch_bounds__(TPB)
qenc_split(const float* __restrict__ x,     // [8192]
           const float* __restrict__ rot,   // [14,3]
           const float* __restrict__ ent,   // [13]
           const float* __restrict__ W1,    // [14]
           const float* __restrict__ b1,    // [14]
           const float* __restrict__ W2,    // [14,16384]
           const float* __restrict__ b2,    // [16384]
           float* __restrict__ out)
{
    constexpr size_t ROW_F  = CPLX ? 2 * (size_t)DIM : (size_t)DIM; // floats/row
    constexpr size_t HEADS4 = ROW_F / 4;                            // float4s/row
    constexpr size_t TOT4   = (size_t)NPOS * HEADS4;                // float4s total
    const int tid = threadIdx.x;

    if (blockIdx.x >= NCOMP) {
        // ---- fill role: linear grid-stride sweep, plain float4 stores ----
        const size_t gtid    = ((size_t)blockIdx.x - NCOMP) * TPB + tid;
        const size_t gstride = (size_t)NFILL * TPB;   // 262,144 float4s
        vf4 z = {0.f, 0.f, 0.f, 0.f};
#pragma unroll 8
        for (size_t i4 = gtid; i4 < TOT4; i4 += gstride) {
            if ((i4 & (HEADS4 - 1)) != 0)             // skip 16B row heads
                *reinterpret_cast<vf4*>(out + 4 * i4) = z;
        }
        return;
    }

    // ---------------- compute role (R4's proven body) ----------------
    __shared__ float sh_h[PCOMP * 16];   // h rows padded to 16 floats
    __shared__ float red[4][PCOMP];      // 4 waves x P partial denominators
    __shared__ float sh_tot_re, sh_tot_im;

    const int wid  = tid >> 6;
    const int lane = tid & 63;
    const long long pos0 = (long long)blockIdx.x * PCOMP;

    // prologue: h = tanh(x*W1 + b1) for our 16 positions (224 threads)
    if (tid < PCOMP * NQ) {
        const int p = tid / NQ;
        const int k = tid - p * NQ;
        sh_h[p * 16 + k] = tanhf(x[pos0 + p] * W1[k] + b1[k]);
    }
    // total = prod(rot_factors) * prod(ent_factors) — one otherwise-idle thread
    if (tid == 240) {
        float tre = 1.0f, tim = 0.0f;
        for (int q = 0; q < NQ; ++q) {
            const float a0 = 0.5f * rot[q * 3 + 0];
            const float a1 = 0.5f * rot[q * 3 + 1];
            const float a2 = 0.5f * rot[q * 3 + 2];
            const float fre = cosf(a0) * cosf(a1) * cosf(a2);
            const float fim = sinf(a0) * sinf(a1) * sinf(a2);
            const float nre = tre * fre - tim * fim;
            const float nim = tre * fim + tim * fre;
            tre = nre; tim = nim;
        }
        for (int q = 0; q < NQ - 1; ++q) {
            const float cs  = 1.0f / (1.0f + __expf(-ent[q]));
            const float nre = tre * cs - tim * (1.0f - cs);
            const float nim = tre * (1.0f - cs) + tim * cs;
            tre = nre; tim = nim;
        }
        sh_tot_re = tre; sh_tot_im = tim;
    }
    __syncthreads();

    float acc[PCOMP];
#pragma unroll
    for (int p = 0; p < PCOMP; ++p) acc[p] = 0.0f;

    // main loop: pure compute, no stores. |z| <~ 1.2 so plain exp-sum is
    // numerically fine (reference's max-subtraction cancels in the d=0 ratio).
    constexpr int ITERS = DIM / (4 * TPB);   // 16
    for (int i = 0; i < ITERS; ++i) {
        const int d = 4 * (tid + TPB * i);
        float4 wv[NQ];
#pragma unroll
        for (int k = 0; k < NQ; ++k)
            wv[k] = *reinterpret_cast<const float4*>(W2 + (size_t)k * DIM + d);
        const float4 bb = *reinterpret_cast<const float4*>(b2 + d);

#pragma unroll
        for (int p = 0; p < PCOMP; ++p) {
            const float4 ha = *reinterpret_cast<const float4*>(&sh_h[p * 16 + 0]);
            const float4 hb = *reinterpret_cast<const float4*>(&sh_h[p * 16 + 4]);
            const float4 hc = *reinterpret_cast<const float4*>(&sh_h[p * 16 + 8]);
            const float2 he = *reinterpret_cast<const float2*>(&sh_h[p * 16 + 12]);
            const float hh[NQ] = {ha.x, ha.y, ha.z, ha.w,
                                  hb.x, hb.y, hb.z, hb.w,
                                  hc.x, hc.y, hc.z, hc.w,
                                  he.x, he.y};
            float za = bb.x, zb = bb.y, zc = bb.z, zd = bb.w;
#pragma unroll
            for (int k = 0; k < NQ; ++k) {
                za = fmaf(hh[k], wv[k].x, za);
                zb = fmaf(hh[k], wv[k].y, zb);
                zc = fmaf(hh[k], wv[k].z, zc);
                zd = fmaf(hh[k], wv[k].w, zd);
            }
            acc[p] += (__expf(za) + __expf(zb)) + (__expf(zc) + __expf(zd));
        }
    }

    // reduction: wave shuffle, then 4 partials per p in LDS
#pragma unroll
    for (int p = 0; p < PCOMP; ++p) {
        float v = acc[p];
#pragma unroll
        for (int off = 32; off > 0; off >>= 1)
            v += __shfl_down(v, off, 64);
        if (lane == 0) red[wid][p] = v;
    }
    __syncthreads();

    // epilogue: 16 threads, one position each — write the full 16B head
    if (tid < PCOMP) {
        const float denom = (red[0][tid] + red[1][tid]) + (red[2][tid] + red[3][tid]);
        float z0 = b2[0];
#pragma unroll
        for (int k = 0; k < NQ; ++k)
            z0 = fmaf(sh_h[tid * 16 + k], W2[(size_t)k * DIM], z0);
        const float w0 = __expf(z0) / denom;
        vf4 head;
        if constexpr (CPLX) head = {sh_tot_re * w0, sh_tot_im * w0, 0.f, 0.f};
        else                head = {sh_tot_re * w0, 0.f, 0.f, 0.f};
        *reinterpret_cast<vf4*>(out + (size_t)(pos0 + tid) * ROW_F) = head;
    }
}

extern "C" void kernel_launch(void* const* d_in, const int* in_sizes, int n_in,
                              void* d_out, int out_size, void* d_ws, size_t ws_size,
                              hipStream_t stream) {
    (void)in_sizes; (void)n_in; (void)d_ws; (void)ws_size;
    const float* x   = (const float*)d_in[0];
    const float* rot = (const float*)d_in[1];
    const float* ent = (const float*)d_in[2];
    const float* W1  = (const float*)d_in[3];
    const float* b1  = (const float*)d_in[4];
    const float* W2  = (const float*)d_in[5];
    const float* b2  = (const float*)d_in[6];
    float* out = (float*)d_out;

    const long long cplx_elems = (long long)NPOS * 2LL * DIM;  // 268,435,456
    if ((long long)out_size >= cplx_elems) {
        qenc_split<true><<<NCOMP + NFILL, TPB, 0, stream>>>(x, rot, ent, W1, b1, W2, b2, out);
    } else {
        qenc_split<false><<<NCOMP + NFILL, TPB, 0, stream>>>(x, rot, ent, W1, b1, W2, b2, out);
    }
}

// Round 8
// 570.053 us; speedup vs baseline: 1.1846x; 1.1846x over previous
//
#include <hip/hip_runtime.h>
#include <math.h>

// Problem constants (from reference)
constexpr int NQ    = 14;        // qubits
constexpr int DIM   = 16384;     // 2^14 state dim
constexpr int BATCH = 4;
constexpr int SEQ   = 2048;
constexpr int NPOS  = BATCH * SEQ;   // 8192 (b,s) positions
constexpr int P     = 4;             // positions per block
constexpr int TPB   = 256;           // threads per block

// native clang vector types — __builtin_nontemporal_store requires these
typedef float vf4 __attribute__((ext_vector_type(4)));
typedef float vf2 __attribute__((ext_vector_type(2)));

// block-uniform float -> SGPR (readfirstlane marks the value uniform)
__device__ __forceinline__ float uniform_f(float v) {
    return __int_as_float(__builtin_amdgcn_readfirstlane(__float_as_int(v)));
}

// Output is [B,S,DIM] where only d=0 of each (b,s) row is nonzero:
//   out[b,s,0] = total * softmax(z)[0],  z = tanh(x*W1+b1) @ W2 + b2
// CPLX=true : out_size = NPOS*2*DIM floats (complex64 as re,im pairs) — the
//             layout the harness actually uses. CPLX=false: real-only fallback.
// Everything except d=0 must be zero-filled (harness poisons d_out each call).
//
// R7: REVERT to the R0 kernel — best of 7 measured structures (567.7 us).
// Session ledger (total us / our-part after 342us harness poison):
//   R0 fused+nt 567.7/226 | R3 fused+plain 578/236 | R2 phase-split 586/244
//   R1 reg-dbuf 591/249   | R5 split+nt-fill 633/291 | R4 memset+comp 635/293
//   R6 split+linear-fill 675/333
// Structural constraint: 342us poison (fixed) + ~226us to emit the 1.07GiB
// output (floor demonstrated 6 ways; even hipMemsetAsync-as-graph-node runs
// ~4.2 TB/s here — rocclr's out-of-capture 6.28 TB/s fill is not reproducible
// from inside our captured launch context). Composite floor ~= 568us = R0.

template <bool CPLX>
__global__ void __launch_bounds__(TPB)
qenc_kernel(const float* __restrict__ x,     // [8192]
            const float* __restrict__ rot,   // [14,3]
            const float* __restrict__ ent,   // [13]
            const float* __restrict__ W1,    // [14]
            const float* __restrict__ b1,    // [14]
            const float* __restrict__ W2,    // [14,16384]
            const float* __restrict__ b2,    // [16384]
            float* __restrict__ out)
{
    __shared__ float sh_h[P * NQ];
    __shared__ float sh_tot_re, sh_tot_im;
    __shared__ float sh_z0[P];
    __shared__ float red[4][P];   // 4 waves x P partial denominators

    const int tid  = threadIdx.x;
    const int wid  = tid >> 6;
    const int lane = tid & 63;
    const long long pos0 = (long long)blockIdx.x * P;

    // --- prologue: h = tanh(x*W1 + b1) for our P positions (wave 0) ---
    if (tid < P * NQ) {
        const int p = tid / NQ;
        const int k = tid - p * NQ;
        sh_h[tid] = tanhf(x[pos0 + p] * W1[k] + b1[k]);
    }
    // total = prod(rot_factors) * prod(ent_factors) — one thread in wave 1
    if (tid == 64) {
        float tre = 1.0f, tim = 0.0f;
        for (int q = 0; q < NQ; ++q) {
            const float a0 = 0.5f * rot[q * 3 + 0];
            const float a1 = 0.5f * rot[q * 3 + 1];
            const float a2 = 0.5f * rot[q * 3 + 2];
            const float fre = cosf(a0) * cosf(a1) * cosf(a2);
            const float fim = sinf(a0) * sinf(a1) * sinf(a2);
            const float nre = tre * fre - tim * fim;
            const float nim = tre * fim + tim * fre;
            tre = nre; tim = nim;
        }
        for (int q = 0; q < NQ - 1; ++q) {
            const float cs  = 1.0f / (1.0f + __expf(-ent[q]));
            const float nre = tre * cs - tim * (1.0f - cs);
            const float nim = tre * (1.0f - cs) + tim * cs;
            tre = nre; tim = nim;
        }
        sh_tot_re = tre; sh_tot_im = tim;
    }
    __syncthreads();

    // h is block-uniform: pull into SGPRs so the 14x4 values don't eat VGPRs
    float h[P][NQ];
#pragma unroll
    for (int p = 0; p < P; ++p)
#pragma unroll
        for (int k = 0; k < NQ; ++k)
            h[p][k] = uniform_f(sh_h[p * NQ + k]);

    float acc[P];
#pragma unroll
    for (int p = 0; p < P; ++p) acc[p] = 0.0f;

    // --- main loop: 4 consecutive d per thread per iter (float4 W2 loads) ---
    // |z| <~ 1.2 (|h|<=1, W2 ~ N(0,0.01)) so plain exp-sum is numerically fine
    // (the reference's max-subtraction cancels exactly in the d=0 ratio).
    constexpr int ITERS = DIM / (4 * TPB);   // 16
    for (int i = 0; i < ITERS; ++i) {
        const int d = 4 * (tid + TPB * i);
        float4 wv[NQ];
#pragma unroll
        for (int k = 0; k < NQ; ++k)
            wv[k] = *reinterpret_cast<const float4*>(W2 + (size_t)k * DIM + d);
        const float4 bb = *reinterpret_cast<const float4*>(b2 + d);
        const bool d0 = (d == 0);   // only tid==0, i==0
#pragma unroll
        for (int p = 0; p < P; ++p) {
            float za = bb.x, zb = bb.y, zc = bb.z, zd = bb.w;
#pragma unroll
            for (int k = 0; k < NQ; ++k) {
                za = fmaf(h[p][k], wv[k].x, za);
                zb = fmaf(h[p][k], wv[k].y, zb);
                zc = fmaf(h[p][k], wv[k].z, zc);
                zd = fmaf(h[p][k], wv[k].w, zd);
            }
            acc[p] += (__expf(za) + __expf(zb)) + (__expf(zc) + __expf(zd));

            if constexpr (CPLX) {
                float* rowp = out + (size_t)(pos0 + p) * (2 * (size_t)DIM) + 2 * d;
                vf4 z4 = {0.f, 0.f, 0.f, 0.f};
                if (!d0) {
                    __builtin_nontemporal_store(z4, reinterpret_cast<vf4*>(rowp));
                    __builtin_nontemporal_store(z4, reinterpret_cast<vf4*>(rowp + 4));
                } else {
                    sh_z0[p] = za;   // leave (re,im) of d=0 for the epilogue
                    vf2 z2 = {0.f, 0.f};
                    __builtin_nontemporal_store(z2, reinterpret_cast<vf2*>(rowp + 2));
                    __builtin_nontemporal_store(z4, reinterpret_cast<vf4*>(rowp + 4));
                }
            } else {
                float* rowp = out + (size_t)(pos0 + p) * (size_t)DIM + d;
                if (!d0) {
                    vf4 z4 = {0.f, 0.f, 0.f, 0.f};
                    __builtin_nontemporal_store(z4, reinterpret_cast<vf4*>(rowp));
                } else {
                    sh_z0[p] = za;
                    __builtin_nontemporal_store(0.f, rowp + 1);
                    __builtin_nontemporal_store(0.f, rowp + 2);
                    __builtin_nontemporal_store(0.f, rowp + 3);
                }
            }
        }
    }

    // --- reduction: wave shuffle, then 4 partials per p in LDS ---
#pragma unroll
    for (int p = 0; p < P; ++p) {
        float v = acc[p];
#pragma unroll
        for (int off = 32; off > 0; off >>= 1)
            v += __shfl_down(v, off, 64);
        if (lane == 0) red[wid][p] = v;
    }
    __syncthreads();
    if (tid < P) {
        const float denom = (red[0][tid] + red[1][tid]) + (red[2][tid] + red[3][tid]);
        const float w0 = __expf(sh_z0[tid]) / denom;
        const size_t stride = CPLX ? 2 * (size_t)DIM : (size_t)DIM;
        float* rowp = out + (size_t)(pos0 + tid) * stride;
        rowp[0] = sh_tot_re * w0;
        if constexpr (CPLX) rowp[1] = sh_tot_im * w0;
    }
}

extern "C" void kernel_launch(void* const* d_in, const int* in_sizes, int n_in,
                              void* d_out, int out_size, void* d_ws, size_t ws_size,
                              hipStream_t stream) {
    (void)in_sizes; (void)n_in; (void)d_ws; (void)ws_size;
    const float* x   = (const float*)d_in[0];
    const float* rot = (const float*)d_in[1];
    const float* ent = (const float*)d_in[2];
    const float* W1  = (const float*)d_in[3];
    const float* b1  = (const float*)d_in[4];
    const float* W2  = (const float*)d_in[5];
    const float* b2  = (const float*)d_in[6];
    float* out = (float*)d_out;

    const long long cplx_elems = (long long)NPOS * 2LL * DIM;  // 268,435,456
    if ((long long)out_size >= cplx_elems) {
        qenc_kernel<true><<<NPOS / P, TPB, 0, stream>>>(x, rot, ent, W1, b1, W2, b2, out);
    } else {
        qenc_kernel<false><<<NPOS / P, TPB, 0, stream>>>(x, rot, ent, W1, b1, W2, b2, out);
    }
}